// Round 1
// baseline (1031.054 us; speedup 1.0000x reference)
//
#include <hip/hip_runtime.h>

#define LNEPS 1e-5f

typedef unsigned short ushort_t;
typedef __attribute__((ext_vector_type(8))) short short8;   // bf16x8 MFMA frag
typedef __attribute__((ext_vector_type(4))) float f32x4;    // fp32x4 accum frag

__device__ inline unsigned short f2b(float f) {
    union { float f; unsigned int u; } c; c.f = f;
    unsigned int u = c.u;
    unsigned int r = (u + 0x7FFFu + ((u >> 16) & 1u)) >> 16;  // RNE
    return (unsigned short)r;
}

// ---------------------------------------------------------------------------
// Weight conversion: eu1_w [4][384][512] -> w1T bf16 [4][512][384]
//                    eu2_w [4][512][128] -> w2T bf16 [4][128][512]
// ---------------------------------------------------------------------------
__global__ void k_convw(const float* __restrict__ w1, const float* __restrict__ w2,
                        ushort_t* __restrict__ w1T, ushort_t* __restrict__ w2T) {
    int idx = blockIdx.x * 256 + threadIdx.x;
    if (idx < 4 * 512 * 384) {
        int l = idx / (512 * 384);
        int rem = idx % (512 * 384);
        int n = rem / 384;
        int k = rem % 384;
        w1T[idx] = f2b(w1[((size_t)l * 384 + k) * 512 + n]);
    }
    if (idx < 4 * 128 * 512) {
        int l = idx / (128 * 512);
        int rem = idx % (128 * 512);
        int n = rem / 512;
        int k = rem % 512;
        w2T[idx] = f2b(w2[((size_t)l * 512 + k) * 128 + n]);
    }
}

// ---------------------------------------------------------------------------
// Edge init: dist, adj, edges = relu(LN(dist*ee_w + ee_b))   one wave per row
// ---------------------------------------------------------------------------
__global__ void k_init(const float* __restrict__ coords,
                       const float* __restrict__ ee_w, const float* __restrict__ ee_b,
                       const float* __restrict__ ee_g, const float* __restrict__ ee_bt,
                       float* __restrict__ ed, float* __restrict__ adjf) {
    int r = blockIdx.x * 4 + (threadIdx.x >> 6);
    int lane = threadIdx.x & 63;
    int i = r >> 8, j = r & 255;
    float dx = coords[i * 3 + 0] - coords[j * 3 + 0];
    float dy = coords[i * 3 + 1] - coords[j * 3 + 1];
    float dz = coords[i * 3 + 2] - coords[j * 3 + 2];
    float sq = dx * dx + dy * dy + dz * dz;
    float dist = sq > 0.f ? sqrtf(sq) : 0.f;
    if (lane == 0) adjf[r] = dist < 10.f ? 1.f : 0.f;
    float e0 = dist * ee_w[lane] + ee_b[lane];
    float e1 = dist * ee_w[lane + 64] + ee_b[lane + 64];
    float s = e0 + e1, q = e0 * e0 + e1 * e1;
    #pragma unroll
    for (int off = 1; off < 64; off <<= 1) {
        s += __shfl_xor(s, off, 64);
        q += __shfl_xor(q, off, 64);
    }
    float mean = s * (1.f / 128.f);
    float var = q * (1.f / 128.f) - mean * mean;
    float rs = rsqrtf(var + LNEPS);
    ed[(size_t)r * 128 + lane]      = fmaxf((e0 - mean) * rs * ee_g[lane] + ee_bt[lane], 0.f);
    ed[(size_t)r * 128 + lane + 64] = fmaxf((e1 - mean) * rs * ee_g[lane + 64] + ee_bt[lane + 64], 0.f);
}

// ---------------------------------------------------------------------------
// nd fp32 -> bf16 copy (32768 elems)
// ---------------------------------------------------------------------------
__global__ void k_b16(const float* __restrict__ src, ushort_t* __restrict__ dst) {
    int idx = blockIdx.x * 256 + threadIdx.x;
    dst[idx] = f2b(src[idx]);
}

// ---------------------------------------------------------------------------
// msgs[r] = adj[r] * dot(ed[r][:], nd[i][:])   one wave per row
// ---------------------------------------------------------------------------
__global__ void k_msgs(const float* __restrict__ ed, const float* __restrict__ nd,
                       const float* __restrict__ adjf, float* __restrict__ msgs) {
    int r = blockIdx.x * 4 + (threadIdx.x >> 6);
    int lane = threadIdx.x & 63;
    int i = r >> 8;
    const float* er = ed + (size_t)r * 128;
    const float* nr = nd + (size_t)i * 128;
    float sum = er[lane] * nr[lane] + er[lane + 64] * nr[lane + 64];
    #pragma unroll
    for (int off = 1; off < 64; off <<= 1) sum += __shfl_xor(sum, off, 64);
    if (lane == 0) msgs[r] = adjf[r] * sum;
}

// ---------------------------------------------------------------------------
// Generic fp32 row-MLP: out = [res +] relu(LN(concat(in0,in1) @ W1 + b1)) @ W2 + b2
// one block (512 threads) per row; K = w0 + w1n <= 384; O <= 128
// ---------------------------------------------------------------------------
__global__ __launch_bounds__(512) void k_mlp(
    const float* __restrict__ in0, int w0, const float* __restrict__ in1, int w1n,
    const float* __restrict__ W1, const float* __restrict__ b1,
    const float* __restrict__ g, const float* __restrict__ bt,
    const float* __restrict__ W2, const float* __restrict__ b2, int O,
    const float* __restrict__ res, float* __restrict__ out) {
    __shared__ float ni[384];
    __shared__ float hsh[512];
    __shared__ float part[4][128];
    __shared__ float red[16];
    int row = blockIdx.x;
    int t = threadIdx.x;
    int K = w0 + w1n;
    if (t < w0) ni[t] = in0[(size_t)row * w0 + t];
    else if (t < K) ni[t] = in1[(size_t)row * w1n + (t - w0)];
    __syncthreads();
    float acc = b1[t];
    #pragma unroll 4
    for (int k = 0; k < K; ++k) acc += ni[k] * W1[(size_t)k * 512 + t];
    float s = acc, q = acc * acc;
    #pragma unroll
    for (int off = 1; off < 64; off <<= 1) {
        s += __shfl_xor(s, off, 64);
        q += __shfl_xor(q, off, 64);
    }
    int wv = t >> 6;
    if ((t & 63) == 0) { red[wv] = s; red[8 + wv] = q; }
    __syncthreads();
    float S = 0.f, Q = 0.f;
    #pragma unroll
    for (int w = 0; w < 8; ++w) { S += red[w]; Q += red[8 + w]; }
    float mean = S * (1.f / 512.f);
    float var = Q * (1.f / 512.f) - mean * mean;
    float rs = rsqrtf(var + LNEPS);
    hsh[t] = fmaxf((acc - mean) * rs * g[t] + bt[t], 0.f);
    __syncthreads();
    int qd = t >> 7, c = t & 127;
    float pacc = 0.f;
    if (c < O) {
        #pragma unroll 4
        for (int kk = 0; kk < 128; ++kk)
            pacc += hsh[qd * 128 + kk] * W2[(size_t)(qd * 128 + kk) * O + c];
    }
    part[qd][c] = pacc;
    __syncthreads();
    if (t < O) {
        float v = part[0][t] + part[1][t] + part[2][t] + part[3][t] + b2[t];
        if (res) v += res[(size_t)row * O + t];
        out[(size_t)row * O + t] = v;
    }
}

// ---------------------------------------------------------------------------
// Fused edge update (in-place on ed), bf16 MFMA.
// Block: 256 threads (4 waves), 64 rows. ei=[ed | nd_i | nd_j] (384) -> h(512)
// -> LN -> relu -> @W2 (128) -> + ed + b2.
// LDS (64KB union): phase A: ei [64][48 chunks of 16B, XOR-swizzled]
//                   phase B: red[4][64][2] @0, stats[64][2] @2048
//                   phase C: h  [64][64 chunks of 16B, XOR-swizzled]
// ---------------------------------------------------------------------------
__global__ __launch_bounds__(256) void k_edge(
    float* ed, const ushort_t* __restrict__ ndb,
    const ushort_t* __restrict__ w1T, const float* __restrict__ b1,
    const float* __restrict__ g, const float* __restrict__ bt,
    const ushort_t* __restrict__ w2T, const float* __restrict__ b2) {
    __shared__ char smem[65536];
    const int tid = threadIdx.x;
    const int w = tid >> 6, lane = tid & 63;
    const int l15 = lane & 15, lhi = lane >> 4;
    const int rbase = blockIdx.x * 64;

    // ---- phase A: stage ei [64][384] as bf16, 16B chunks XOR-swizzled by row&7
    #pragma unroll 1
    for (int c = tid; c < 64 * 48; c += 256) {
        int row = c / 48, ch = c % 48;
        int col8 = ch * 8;
        int R = rbase + row;
        uint4 pk;
        if (col8 < 128) {
            const float4* sp = (const float4*)(ed + (size_t)R * 128 + col8);
            float4 v0 = sp[0], v1 = sp[1];
            pk.x = (unsigned)f2b(v0.x) | ((unsigned)f2b(v0.y) << 16);
            pk.y = (unsigned)f2b(v0.z) | ((unsigned)f2b(v0.w) << 16);
            pk.z = (unsigned)f2b(v1.x) | ((unsigned)f2b(v1.y) << 16);
            pk.w = (unsigned)f2b(v1.z) | ((unsigned)f2b(v1.w) << 16);
        } else if (col8 < 256) {
            int i = R >> 8;
            pk = *(const uint4*)(ndb + i * 128 + (col8 - 128));
        } else {
            int j = R & 255;
            pk = *(const uint4*)(ndb + j * 128 + (col8 - 256));
        }
        *(uint4*)(smem + row * 768 + ((ch ^ (row & 7)) * 16)) = pk;
    }
    __syncthreads();

    // ---- phase B: GEMM1. wave w -> hidden cols [w*128, w*128+128)
    f32x4 acc[4][8];
    f32x4 zero = {0.f, 0.f, 0.f, 0.f};
    #pragma unroll
    for (int m = 0; m < 4; ++m)
        #pragma unroll
        for (int n = 0; n < 8; ++n) acc[m][n] = zero;

    const int cw = w * 128;
    #pragma unroll 1
    for (int k0 = 0; k0 < 384; k0 += 32) {
        short8 a[4];
        #pragma unroll
        for (int m = 0; m < 4; ++m) {
            int row = m * 16 + l15;
            a[m] = *(const short8*)(smem + row * 768 + ((((k0 >> 3) + lhi) ^ (row & 7)) * 16));
        }
        #pragma unroll
        for (int n = 0; n < 8; ++n) {
            int col = cw + n * 16 + l15;
            short8 b = *(const short8*)(w1T + (size_t)col * 384 + k0 + lhi * 8);
            #pragma unroll
            for (int m = 0; m < 4; ++m)
                acc[m][n] = __builtin_amdgcn_mfma_f32_16x16x32_bf16(a[m], b, acc[m][n], 0, 0, 0);
        }
    }
    __syncthreads();   // ei dead; smem reusable

    // ---- LN: add bias, per-row mean/var over 512 cols (cross-wave via LDS)
    float bias[8], gg[8], bb[8];
    #pragma unroll
    for (int n = 0; n < 8; ++n) {
        int col = cw + n * 16 + l15;
        bias[n] = b1[col]; gg[n] = g[col]; bb[n] = bt[col];
    }
    float s[4][4], q[4][4];
    #pragma unroll
    for (int m = 0; m < 4; ++m)
        #pragma unroll
        for (int e = 0; e < 4; ++e) { s[m][e] = 0.f; q[m][e] = 0.f; }
    #pragma unroll
    for (int m = 0; m < 4; ++m)
        #pragma unroll
        for (int n = 0; n < 8; ++n)
            #pragma unroll
            for (int e = 0; e < 4; ++e) {
                float v = acc[m][n][e] + bias[n];
                acc[m][n][e] = v;
                s[m][e] += v; q[m][e] += v * v;
            }
    #pragma unroll
    for (int off = 1; off < 16; off <<= 1) {
        #pragma unroll
        for (int m = 0; m < 4; ++m)
            #pragma unroll
            for (int e = 0; e < 4; ++e) {
                s[m][e] += __shfl_xor(s[m][e], off, 64);
                q[m][e] += __shfl_xor(q[m][e], off, 64);
            }
    }
    float* red = (float*)smem;               // [4][64][2]
    float* stats = (float*)(smem + 2048);    // [64][2]
    if (l15 == 0) {
        #pragma unroll
        for (int m = 0; m < 4; ++m)
            #pragma unroll
            for (int e = 0; e < 4; ++e) {
                int row = m * 16 + lhi * 4 + e;
                red[(w * 64 + row) * 2 + 0] = s[m][e];
                red[(w * 64 + row) * 2 + 1] = q[m][e];
            }
    }
    __syncthreads();
    if (tid < 64) {
        float S = 0.f, Q = 0.f;
        #pragma unroll
        for (int ww = 0; ww < 4; ++ww) {
            S += red[(ww * 64 + tid) * 2 + 0];
            Q += red[(ww * 64 + tid) * 2 + 1];
        }
        float mean = S * (1.f / 512.f);
        float var = Q * (1.f / 512.f) - mean * mean;
        stats[tid * 2 + 0] = mean;
        stats[tid * 2 + 1] = rsqrtf(var + LNEPS);
    }
    __syncthreads();
    #pragma unroll
    for (int m = 0; m < 4; ++m)
        #pragma unroll
        for (int e = 0; e < 4; ++e) {
            int row = m * 16 + lhi * 4 + e;
            float mean = stats[row * 2 + 0];
            float rs = stats[row * 2 + 1];
            #pragma unroll
            for (int n = 0; n < 8; ++n) {
                float v = (acc[m][n][e] - mean) * rs * gg[n] + bb[n];
                acc[m][n][e] = fmaxf(v, 0.f);
            }
        }
    __syncthreads();   // stats consumed; safe to overwrite with h

    // ---- write h [64][512] bf16, XOR-swizzled
    #pragma unroll
    for (int m = 0; m < 4; ++m)
        #pragma unroll
        for (int n = 0; n < 8; ++n)
            #pragma unroll
            for (int e = 0; e < 4; ++e) {
                int row = m * 16 + lhi * 4 + e;
                int col = cw + n * 16 + l15;
                int addr = row * 1024 + (((col >> 3) ^ (row & 7)) * 16) + (col & 7) * 2;
                *(ushort_t*)(smem + addr) = f2b(acc[m][n][e]);
            }
    __syncthreads();

    // ---- GEMM2: out[64][128] = h @ W2; wave w -> rows [w*16, w*16+16)
    f32x4 acc2[8];
    #pragma unroll
    for (int n = 0; n < 8; ++n) acc2[n] = zero;
    const int rb = w * 16;
    #pragma unroll 1
    for (int k0 = 0; k0 < 512; k0 += 32) {
        int row = rb + l15;
        short8 a = *(const short8*)(smem + row * 1024 + ((((k0 >> 3) + lhi) ^ (row & 7)) * 16));
        #pragma unroll
        for (int n = 0; n < 8; ++n) {
            int col = n * 16 + l15;
            short8 b = *(const short8*)(w2T + (size_t)col * 512 + k0 + lhi * 8);
            acc2[n] = __builtin_amdgcn_mfma_f32_16x16x32_bf16(a, b, acc2[n], 0, 0, 0);
        }
    }
    // ---- epilogue: residual + bias, in-place write
    #pragma unroll
    for (int n = 0; n < 8; ++n) {
        int col = n * 16 + l15;
        float bc = b2[col];
        #pragma unroll
        for (int e = 0; e < 4; ++e) {
            int row = rb + lhi * 4 + e;
            size_t off = (size_t)(rbase + row) * 128 + col;
            ed[off] = acc2[n][e] + bc + ed[off];
        }
    }
}

// ---------------------------------------------------------------------------
extern "C" void kernel_launch(void* const* d_in, const int* in_sizes, int n_in,
                              void* d_out, int out_size, void* d_ws, size_t ws_size,
                              hipStream_t stream) {
    const float* nodes  = (const float*)d_in[0];
    const float* coords = (const float*)d_in[1];
    const float* ee_w   = (const float*)d_in[2];
    const float* ee_b   = (const float*)d_in[3];
    const float* ee_g   = (const float*)d_in[4];
    const float* ee_bt  = (const float*)d_in[5];
    const float* nu1_w  = (const float*)d_in[6];
    const float* nu1_b  = (const float*)d_in[7];
    const float* nu_g   = (const float*)d_in[8];
    const float* nu_bt  = (const float*)d_in[9];
    const float* nu2_w  = (const float*)d_in[10];
    const float* nu2_b  = (const float*)d_in[11];
    const float* eu1_w  = (const float*)d_in[12];
    const float* eu1_b  = (const float*)d_in[13];
    const float* eu_g   = (const float*)d_in[14];
    const float* eu_bt  = (const float*)d_in[15];
    const float* eu2_w  = (const float*)d_in[16];
    const float* eu2_b  = (const float*)d_in[17];
    const float* sp1_w  = (const float*)d_in[18];
    const float* sp1_b  = (const float*)d_in[19];
    const float* sp_g   = (const float*)d_in[20];
    const float* sp_bt  = (const float*)d_in[21];
    const float* sp2_w  = (const float*)d_in[22];
    const float* sp2_b  = (const float*)d_in[23];
    const float* no1_w  = (const float*)d_in[24];
    const float* no1_b  = (const float*)d_in[25];
    const float* no_g   = (const float*)d_in[26];
    const float* no_bt  = (const float*)d_in[27];
    const float* no2_w  = (const float*)d_in[28];
    const float* no2_b  = (const float*)d_in[29];

    char* p = (char*)d_ws;
    float* ed      = (float*)p;     p += (size_t)65536 * 128 * 4;   // 33.5 MB, in-place edges
    float* ndA     = (float*)p;     p += 256 * 128 * 4;
    float* ndB     = (float*)p;     p += 256 * 128 * 4;
    ushort_t* ndb  = (ushort_t*)p;  p += 256 * 128 * 2;
    float* msgs    = (float*)p;     p += 65536 * 4;
    float* adjf    = (float*)p;     p += 65536 * 4;
    ushort_t* w1T  = (ushort_t*)p;  p += (size_t)4 * 512 * 384 * 2;
    ushort_t* w2T  = (ushort_t*)p;  p += (size_t)4 * 128 * 512 * 2;

    k_convw<<<3072, 256, 0, stream>>>(eu1_w, eu2_w, w1T, w2T);
    k_init<<<16384, 256, 0, stream>>>(coords, ee_w, ee_b, ee_g, ee_bt, ed, adjf);

    const float* nd_cur = nodes;
    float* nd_bufs[2] = {ndA, ndB};
    for (int l = 0; l < 4; ++l) {
        float* nd_next = nd_bufs[l & 1];
        k_b16<<<128, 256, 0, stream>>>(nd_cur, ndb);
        k_msgs<<<16384, 256, 0, stream>>>(ed, nd_cur, adjf, msgs);
        k_mlp<<<256, 512, 0, stream>>>(nd_cur, 128, msgs, 256,
            nu1_w + (size_t)l * 384 * 512, nu1_b + l * 512, nu_g + l * 512, nu_bt + l * 512,
            nu2_w + (size_t)l * 512 * 128, nu2_b + l * 128, 128, nd_cur, nd_next);
        k_edge<<<1024, 256, 0, stream>>>(ed, ndb,
            w1T + (size_t)l * 512 * 384, eu1_b + l * 512, eu_g + l * 512, eu_bt + l * 512,
            w2T + (size_t)l * 128 * 512, eu2_b + l * 128);
        nd_cur = nd_next;
    }

    float* out_nodes  = (float*)d_out;
    float* out_coords = out_nodes + 32768;
    k_mlp<<<256, 512, 0, stream>>>(nd_cur, 128, nullptr, 0,
        no1_w, no1_b, no_g, no_bt, no2_w, no2_b, 128, nullptr, out_nodes);
    k_mlp<<<256, 512, 0, stream>>>(out_nodes, 128, nullptr, 0,
        sp1_w, sp1_b, sp_g, sp_bt, sp2_w, sp2_b, 3, nullptr, out_coords);
}

// Round 2
// 884.223 us; speedup vs baseline: 1.1661x; 1.1661x over previous
//
#include <hip/hip_runtime.h>

#define LNEPS 1e-5f

typedef unsigned short ushort_t;
typedef __attribute__((ext_vector_type(8))) short short8;   // bf16x8 MFMA frag
typedef __attribute__((ext_vector_type(4))) float f32x4;    // fp32x4 accum frag

__device__ inline unsigned short f2b(float f) {
    union { float f; unsigned int u; } c; c.f = f;
    unsigned int u = c.u;
    unsigned int r = (u + 0x7FFFu + ((u >> 16) & 1u)) >> 16;  // RNE
    return (unsigned short)r;
}

// ---------------------------------------------------------------------------
// Weight packing into MFMA B-fragment order (wave-contiguous 1KB loads).
// w1P: [L=4][ctile=32][kb=12][lane=64][8]  from eu1_w [4][384][512]
// w2P: [L=4][ctile=8 ][kb=16][lane=64][8]  from eu2_w [4][512][128]
// frag element: col = ctile*16 + (lane&15), k = kb*32 + (lane>>4)*8 + e
// ---------------------------------------------------------------------------
__global__ void k_convw(const float* __restrict__ w1, const float* __restrict__ w2,
                        ushort_t* __restrict__ w1P, ushort_t* __restrict__ w2P) {
    int idx = blockIdx.x * 256 + threadIdx.x;   // chunk index (8 elems each)
    if (idx < 4 * 32 * 12 * 64) {
        int l = idx / 24576, r = idx % 24576;
        int c = r / 768;  r %= 768;
        int kb = r / 64, lane = r % 64;
        int col = c * 16 + (lane & 15);
        int k0 = kb * 32 + (lane >> 4) * 8;
        ushort_t o[8];
        #pragma unroll
        for (int e = 0; e < 8; ++e)
            o[e] = f2b(w1[((size_t)l * 384 + k0 + e) * 512 + col]);
        *(uint4*)(w1P + (size_t)idx * 8) = *(uint4*)o;
    }
    if (idx < 4 * 8 * 16 * 64) {
        int l = idx / 8192, r = idx % 8192;
        int c = r / 1024; r %= 1024;
        int kb = r / 64, lane = r % 64;
        int col = c * 16 + (lane & 15);
        int k0 = kb * 32 + (lane >> 4) * 8;
        ushort_t o[8];
        #pragma unroll
        for (int e = 0; e < 8; ++e)
            o[e] = f2b(w2[((size_t)l * 512 + k0 + e) * 128 + col]);
        *(uint4*)(w2P + (size_t)idx * 8) = *(uint4*)o;
    }
}

// ---------------------------------------------------------------------------
// Edge init: dist, adj, edges = relu(LN(dist*ee_w + ee_b))   one wave per row
// ---------------------------------------------------------------------------
__global__ void k_init(const float* __restrict__ coords,
                       const float* __restrict__ ee_w, const float* __restrict__ ee_b,
                       const float* __restrict__ ee_g, const float* __restrict__ ee_bt,
                       float* __restrict__ ed, float* __restrict__ adjf) {
    int r = blockIdx.x * 4 + (threadIdx.x >> 6);
    int lane = threadIdx.x & 63;
    int i = r >> 8, j = r & 255;
    float dx = coords[i * 3 + 0] - coords[j * 3 + 0];
    float dy = coords[i * 3 + 1] - coords[j * 3 + 1];
    float dz = coords[i * 3 + 2] - coords[j * 3 + 2];
    float sq = dx * dx + dy * dy + dz * dz;
    float dist = sq > 0.f ? sqrtf(sq) : 0.f;
    if (lane == 0) adjf[r] = dist < 10.f ? 1.f : 0.f;
    float e0 = dist * ee_w[lane] + ee_b[lane];
    float e1 = dist * ee_w[lane + 64] + ee_b[lane + 64];
    float s = e0 + e1, q = e0 * e0 + e1 * e1;
    #pragma unroll
    for (int off = 1; off < 64; off <<= 1) {
        s += __shfl_xor(s, off, 64);
        q += __shfl_xor(q, off, 64);
    }
    float mean = s * (1.f / 128.f);
    float var = q * (1.f / 128.f) - mean * mean;
    float rs = rsqrtf(var + LNEPS);
    ed[(size_t)r * 128 + lane]      = fmaxf((e0 - mean) * rs * ee_g[lane] + ee_bt[lane], 0.f);
    ed[(size_t)r * 128 + lane + 64] = fmaxf((e1 - mean) * rs * ee_g[lane + 64] + ee_bt[lane + 64], 0.f);
}

// ---------------------------------------------------------------------------
// nd fp32 -> bf16 copy (32768 elems)
// ---------------------------------------------------------------------------
__global__ void k_b16(const float* __restrict__ src, ushort_t* __restrict__ dst) {
    int idx = blockIdx.x * 256 + threadIdx.x;
    dst[idx] = f2b(src[idx]);
}

// ---------------------------------------------------------------------------
// msgs[r] = adj[r] * dot(ed[r][:], nd[i][:])   one wave per row
// ---------------------------------------------------------------------------
__global__ void k_msgs(const float* __restrict__ ed, const float* __restrict__ nd,
                       const float* __restrict__ adjf, float* __restrict__ msgs) {
    int r = blockIdx.x * 4 + (threadIdx.x >> 6);
    int lane = threadIdx.x & 63;
    int i = r >> 8;
    const float* er = ed + (size_t)r * 128;
    const float* nr = nd + (size_t)i * 128;
    float sum = er[lane] * nr[lane] + er[lane + 64] * nr[lane + 64];
    #pragma unroll
    for (int off = 1; off < 64; off <<= 1) sum += __shfl_xor(sum, off, 64);
    if (lane == 0) msgs[r] = adjf[r] * sum;
}

// ---------------------------------------------------------------------------
// Generic fp32 row-MLP: out = [res +] relu(LN(concat(in0,in1) @ W1 + b1)) @ W2 + b2
// one block (512 threads) per row; K = w0 + w1n <= 384; O <= 128
// ---------------------------------------------------------------------------
__global__ __launch_bounds__(512) void k_mlp(
    const float* __restrict__ in0, int w0, const float* __restrict__ in1, int w1n,
    const float* __restrict__ W1, const float* __restrict__ b1,
    const float* __restrict__ g, const float* __restrict__ bt,
    const float* __restrict__ W2, const float* __restrict__ b2, int O,
    const float* __restrict__ res, float* __restrict__ out) {
    __shared__ float ni[384];
    __shared__ float hsh[512];
    __shared__ float part[4][128];
    __shared__ float red[16];
    int row = blockIdx.x;
    int t = threadIdx.x;
    int K = w0 + w1n;
    if (t < w0) ni[t] = in0[(size_t)row * w0 + t];
    else if (t < K) ni[t] = in1[(size_t)row * w1n + (t - w0)];
    __syncthreads();
    float acc = b1[t];
    #pragma unroll 4
    for (int k = 0; k < K; ++k) acc += ni[k] * W1[(size_t)k * 512 + t];
    float s = acc, q = acc * acc;
    #pragma unroll
    for (int off = 1; off < 64; off <<= 1) {
        s += __shfl_xor(s, off, 64);
        q += __shfl_xor(q, off, 64);
    }
    int wv = t >> 6;
    if ((t & 63) == 0) { red[wv] = s; red[8 + wv] = q; }
    __syncthreads();
    float S = 0.f, Q = 0.f;
    #pragma unroll
    for (int w = 0; w < 8; ++w) { S += red[w]; Q += red[8 + w]; }
    float mean = S * (1.f / 512.f);
    float var = Q * (1.f / 512.f) - mean * mean;
    float rs = rsqrtf(var + LNEPS);
    hsh[t] = fmaxf((acc - mean) * rs * g[t] + bt[t], 0.f);
    __syncthreads();
    int qd = t >> 7, c = t & 127;
    float pacc = 0.f;
    if (c < O) {
        #pragma unroll 4
        for (int kk = 0; kk < 128; ++kk)
            pacc += hsh[qd * 128 + kk] * W2[(size_t)(qd * 128 + kk) * O + c];
    }
    part[qd][c] = pacc;
    __syncthreads();
    if (t < O) {
        float v = part[0][t] + part[1][t] + part[2][t] + part[3][t] + b2[t];
        if (res) v += res[(size_t)row * O + t];
        out[(size_t)row * O + t] = v;
    }
}

// ---------------------------------------------------------------------------
// Fused edge update (in-place on ed), bf16 MFMA, packed-fragment weights.
// Block: 256 threads (4 waves), 64 rows.
// LDS 50.5KB: ei [64 rows][48 ch][16B] @0 (48KB)   -- dead after GEMM1
//             h-half [32 rows][64 ch][16B] @0 (32KB, reuses ei region)
//             red [4][64][2] f32 @49152, stats [64][2] f32 @51200
// GEMM2 runs in two 32-row halves to keep LDS at 3 blocks/CU.
// ---------------------------------------------------------------------------
__global__ __launch_bounds__(256, 3) void k_edge(
    float* ed, const ushort_t* __restrict__ ndb,
    const ushort_t* __restrict__ w1P, const float* __restrict__ b1,
    const float* __restrict__ g, const float* __restrict__ bt,
    const ushort_t* __restrict__ w2P, const float* __restrict__ b2) {
    __shared__ char smem[51712];
    const int tid = threadIdx.x;
    const int w = tid >> 6, lane = tid & 63;
    const int l15 = lane & 15, lhi = lane >> 4;
    const int rbase = blockIdx.x * 64;

    // ---- phase A: stage ei [64][384] as bf16, 16B chunks XOR-swizzled by row&7
    #pragma unroll 1
    for (int c = tid; c < 64 * 48; c += 256) {
        int row = c / 48, ch = c % 48;
        int col8 = ch * 8;
        int R = rbase + row;
        uint4 pk;
        if (col8 < 128) {
            const float4* sp = (const float4*)(ed + (size_t)R * 128 + col8);
            float4 v0 = sp[0], v1 = sp[1];
            pk.x = (unsigned)f2b(v0.x) | ((unsigned)f2b(v0.y) << 16);
            pk.y = (unsigned)f2b(v0.z) | ((unsigned)f2b(v0.w) << 16);
            pk.z = (unsigned)f2b(v1.x) | ((unsigned)f2b(v1.y) << 16);
            pk.w = (unsigned)f2b(v1.z) | ((unsigned)f2b(v1.w) << 16);
        } else if (col8 < 256) {
            int i = R >> 8;
            pk = *(const uint4*)(ndb + i * 128 + (col8 - 128));
        } else {
            int j = R & 255;
            pk = *(const uint4*)(ndb + j * 128 + (col8 - 256));
        }
        *(uint4*)(smem + row * 768 + ((ch ^ (row & 7)) * 16)) = pk;
    }
    __syncthreads();

    // ---- GEMM1: wave w -> hidden cols [w*128, w*128+128), acc[m=4 rowtiles][n=8 coltiles]
    f32x4 acc[4][8];
    f32x4 zero = {0.f, 0.f, 0.f, 0.f};
    #pragma unroll
    for (int m = 0; m < 4; ++m)
        #pragma unroll
        for (int n = 0; n < 8; ++n) acc[m][n] = zero;

    const int cw = w * 128;
    const ushort_t* w1w = w1P + (size_t)(w * 8) * 12 * 512;  // wave's ctile base
    #pragma unroll 1
    for (int kb = 0; kb < 12; ++kb) {
        short8 a[4];
        #pragma unroll
        for (int m = 0; m < 4; ++m) {
            int row = m * 16 + l15;
            a[m] = *(const short8*)(smem + row * 768 + (((kb * 4 + lhi) ^ (row & 7)) * 16));
        }
        #pragma unroll
        for (int n = 0; n < 8; ++n) {
            short8 b = *(const short8*)(w1w + ((n * 12 + kb) << 9) + lane * 8);
            #pragma unroll
            for (int m = 0; m < 4; ++m)
                acc[m][n] = __builtin_amdgcn_mfma_f32_16x16x32_bf16(a[m], b, acc[m][n], 0, 0, 0);
        }
    }

    // ---- LN: fold bias, per-row stats (low reg pressure: per-m)
    float* red = (float*)(smem + 49152);     // [4][64][2]
    float* stats = (float*)(smem + 51200);   // [64][2]
    {
        float bias[8];
        #pragma unroll
        for (int n = 0; n < 8; ++n) bias[n] = b1[cw + n * 16 + l15];
        #pragma unroll
        for (int m = 0; m < 4; ++m) {
            float s[4] = {0.f, 0.f, 0.f, 0.f}, q[4] = {0.f, 0.f, 0.f, 0.f};
            #pragma unroll
            for (int n = 0; n < 8; ++n)
                #pragma unroll
                for (int e = 0; e < 4; ++e) {
                    float v = acc[m][n][e] + bias[n];
                    acc[m][n][e] = v;
                    s[e] += v; q[e] += v * v;
                }
            #pragma unroll
            for (int off = 1; off < 16; off <<= 1)
                #pragma unroll
                for (int e = 0; e < 4; ++e) {
                    s[e] += __shfl_xor(s[e], off, 64);
                    q[e] += __shfl_xor(q[e], off, 64);
                }
            if (l15 == 0) {
                #pragma unroll
                for (int e = 0; e < 4; ++e) {
                    int row = m * 16 + lhi * 4 + e;
                    red[(w * 64 + row) * 2 + 0] = s[e];
                    red[(w * 64 + row) * 2 + 1] = q[e];
                }
            }
        }
    }
    __syncthreads();
    if (tid < 64) {
        float S = 0.f, Q = 0.f;
        #pragma unroll
        for (int ww = 0; ww < 4; ++ww) {
            S += red[(ww * 64 + tid) * 2 + 0];
            Q += red[(ww * 64 + tid) * 2 + 1];
        }
        float mean = S * (1.f / 512.f);
        float var = Q * (1.f / 512.f) - mean * mean;
        stats[tid * 2 + 0] = mean;
        stats[tid * 2 + 1] = rsqrtf(var + LNEPS);
    }
    __syncthreads();
    {
        float gg[8], bb[8];
        #pragma unroll
        for (int n = 0; n < 8; ++n) {
            gg[n] = g[cw + n * 16 + l15];
            bb[n] = bt[cw + n * 16 + l15];
        }
        #pragma unroll
        for (int m = 0; m < 4; ++m)
            #pragma unroll
            for (int e = 0; e < 4; ++e) {
                int row = m * 16 + lhi * 4 + e;
                float mean = stats[row * 2 + 0];
                float rs = stats[row * 2 + 1];
                #pragma unroll
                for (int n = 0; n < 8; ++n)
                    acc[m][n][e] = fmaxf((acc[m][n][e] - mean) * rs * gg[n] + bb[n], 0.f);
            }
    }

    // ---- GEMM2 in two 32-row halves (h-half 32KB reuses ei region)
    const int mt = w & 1, cb = (w >> 1) * 4;
    float bc[4];
    #pragma unroll
    for (int n2 = 0; n2 < 4; ++n2) bc[n2] = b2[(cb + n2) * 16 + l15];

    #pragma unroll
    for (int half = 0; half < 2; ++half) {
        __syncthreads();   // half0: stats read done; half1: GEMM2-half0 LDS reads done
        #pragma unroll
        for (int mm = 0; mm < 2; ++mm) {
            #pragma unroll
            for (int n = 0; n < 8; ++n)
                #pragma unroll
                for (int e = 0; e < 4; ++e) {
                    int lr = mm * 16 + lhi * 4 + e;
                    int col = cw + n * 16 + l15;
                    int addr = lr * 1024 + (((col >> 3) ^ (lr & 7)) * 16) + (col & 7) * 2;
                    *(ushort_t*)(smem + addr) = f2b(acc[half * 2 + mm][n][e]);
                }
        }
        __syncthreads();
        f32x4 acc2[4];
        #pragma unroll
        for (int n2 = 0; n2 < 4; ++n2) acc2[n2] = zero;
        #pragma unroll 1
        for (int kb = 0; kb < 16; ++kb) {
            int lr = mt * 16 + l15;
            short8 a = *(const short8*)(smem + lr * 1024 + (((kb * 4 + lhi) ^ (lr & 7)) * 16));
            #pragma unroll
            for (int n2 = 0; n2 < 4; ++n2) {
                short8 b = *(const short8*)(w2P + (((cb + n2) * 16 + kb) << 9) + lane * 8);
                acc2[n2] = __builtin_amdgcn_mfma_f32_16x16x32_bf16(a, b, acc2[n2], 0, 0, 0);
            }
        }
        #pragma unroll
        for (int n2 = 0; n2 < 4; ++n2) {
            int col = (cb + n2) * 16 + l15;
            #pragma unroll
            for (int e = 0; e < 4; ++e) {
                int row = half * 32 + mt * 16 + lhi * 4 + e;
                size_t off = (size_t)(rbase + row) * 128 + col;
                ed[off] = acc2[n2][e] + bc[n2] + ed[off];
            }
        }
    }
}

// ---------------------------------------------------------------------------
extern "C" void kernel_launch(void* const* d_in, const int* in_sizes, int n_in,
                              void* d_out, int out_size, void* d_ws, size_t ws_size,
                              hipStream_t stream) {
    const float* nodes  = (const float*)d_in[0];
    const float* coords = (const float*)d_in[1];
    const float* ee_w   = (const float*)d_in[2];
    const float* ee_b   = (const float*)d_in[3];
    const float* ee_g   = (const float*)d_in[4];
    const float* ee_bt  = (const float*)d_in[5];
    const float* nu1_w  = (const float*)d_in[6];
    const float* nu1_b  = (const float*)d_in[7];
    const float* nu_g   = (const float*)d_in[8];
    const float* nu_bt  = (const float*)d_in[9];
    const float* nu2_w  = (const float*)d_in[10];
    const float* nu2_b  = (const float*)d_in[11];
    const float* eu1_w  = (const float*)d_in[12];
    const float* eu1_b  = (const float*)d_in[13];
    const float* eu_g   = (const float*)d_in[14];
    const float* eu_bt  = (const float*)d_in[15];
    const float* eu2_w  = (const float*)d_in[16];
    const float* eu2_b  = (const float*)d_in[17];
    const float* sp1_w  = (const float*)d_in[18];
    const float* sp1_b  = (const float*)d_in[19];
    const float* sp_g   = (const float*)d_in[20];
    const float* sp_bt  = (const float*)d_in[21];
    const float* sp2_w  = (const float*)d_in[22];
    const float* sp2_b  = (const float*)d_in[23];
    const float* no1_w  = (const float*)d_in[24];
    const float* no1_b  = (const float*)d_in[25];
    const float* no_g   = (const float*)d_in[26];
    const float* no_bt  = (const float*)d_in[27];
    const float* no2_w  = (const float*)d_in[28];
    const float* no2_b  = (const float*)d_in[29];

    char* p = (char*)d_ws;
    float* ed      = (float*)p;     p += (size_t)65536 * 128 * 4;   // 33.5 MB, in-place edges
    float* ndA     = (float*)p;     p += 256 * 128 * 4;
    float* ndB     = (float*)p;     p += 256 * 128 * 4;
    ushort_t* ndb  = (ushort_t*)p;  p += 256 * 128 * 2;
    float* msgs    = (float*)p;     p += 65536 * 4;
    float* adjf    = (float*)p;     p += 65536 * 4;
    ushort_t* w1P  = (ushort_t*)p;  p += (size_t)4 * 512 * 384 * 2;
    ushort_t* w2P  = (ushort_t*)p;  p += (size_t)4 * 128 * 512 * 2;

    k_convw<<<384, 256, 0, stream>>>(eu1_w, eu2_w, w1P, w2P);
    k_init<<<16384, 256, 0, stream>>>(coords, ee_w, ee_b, ee_g, ee_bt, ed, adjf);

    const float* nd_cur = nodes;
    float* nd_bufs[2] = {ndA, ndB};
    for (int l = 0; l < 4; ++l) {
        float* nd_next = nd_bufs[l & 1];
        k_b16<<<128, 256, 0, stream>>>(nd_cur, ndb);
        k_msgs<<<16384, 256, 0, stream>>>(ed, nd_cur, adjf, msgs);
        k_mlp<<<256, 512, 0, stream>>>(nd_cur, 128, msgs, 256,
            nu1_w + (size_t)l * 384 * 512, nu1_b + l * 512, nu_g + l * 512, nu_bt + l * 512,
            nu2_w + (size_t)l * 512 * 128, nu2_b + l * 128, 128, nd_cur, nd_next);
        k_edge<<<1024, 256, 0, stream>>>(ed, ndb,
            w1P + (size_t)l * 196608, eu1_b + l * 512, eu_g + l * 512, eu_bt + l * 512,
            w2P + (size_t)l * 65536, eu2_b + l * 128);
        nd_cur = nd_next;
    }

    float* out_nodes  = (float*)d_out;
    float* out_coords = out_nodes + 32768;
    k_mlp<<<256, 512, 0, stream>>>(nd_cur, 128, nullptr, 0,
        no1_w, no1_b, no_g, no_bt, no2_w, no2_b, 128, nullptr, out_nodes);
    k_mlp<<<256, 512, 0, stream>>>(out_nodes, 128, nullptr, 0,
        sp1_w, sp1_b, sp_g, sp_bt, sp2_w, sp2_b, 3, nullptr, out_coords);
}